// Round 6
// baseline (219.161 us; speedup 1.0000x reference)
//
#include <hip/hip_runtime.h>

// CRF NLL, round 6: exp-space forward recursion, one wave per batch.
// Changes vs r5:
//  - NO local arrays at all: transfer matrix = 64 named scalars (vtgG_J),
//    feats ring = fr0..fr7, broadcast pipeline = named tA*/tB* (alloca-free,
//    so scratch spill is structurally impossible; budget is open via
//    __launch_bounds__(128,1))
//  - exact pow2 rescale EVERY step using the PREVIOUS step's D exponent,
//    folded into fe while the matvec runs -> per-step critical chain is just
//    fmacs -> add tree -> one mul. ksum tracks only APPLIED scales.
#define BB 512
#define SS 512
#define TT 64
#define START_TAG 62
#define STOP_TAG 63

#define LOG2E 1.4426950408889634f
#define LN2   0.6931471805599453f

__device__ __forceinline__ float bcast0(float x) {
    return __int_as_float(__builtin_amdgcn_readfirstlane(__float_as_int(x)));
}
__device__ __forceinline__ float rl_(float x, int l) {
    return __int_as_float(__builtin_amdgcn_readlane(__float_as_int(x), l));
}

// ---- named-scalar transfer matrix: vtgG_J = exp2(trans[8G+J][lane]*log2e) ----
#define VT1(g, j) float vtg##g##_##j = \
    __builtin_amdgcn_exp2f(trans[((g) * 8 + (j)) * TT + lane] * LOG2E);
#define VT_GROUP(g) \
    VT1(g,0) VT1(g,1) VT1(g,2) VT1(g,3) VT1(g,4) VT1(g,5) VT1(g,6) VT1(g,7)

#define RL_GROUP(T, g) \
    T##0 = rl_(E, (g)*8 + 0); T##1 = rl_(E, (g)*8 + 1); \
    T##2 = rl_(E, (g)*8 + 2); T##3 = rl_(E, (g)*8 + 3); \
    T##4 = rl_(E, (g)*8 + 4); T##5 = rl_(E, (g)*8 + 5); \
    T##6 = rl_(E, (g)*8 + 6); T##7 = rl_(E, (g)*8 + 7);

#define FMA_GROUP(T, g) \
    a0 = fmaf(T##0, vtg##g##_0, a0); a1 = fmaf(T##1, vtg##g##_1, a1); \
    a2 = fmaf(T##2, vtg##g##_2, a2); a3 = fmaf(T##3, vtg##g##_3, a3); \
    a0 = fmaf(T##4, vtg##g##_4, a0); a1 = fmaf(T##5, vtg##g##_5, a1); \
    a2 = fmaf(T##6, vtg##g##_6, a2); a3 = fmaf(T##7, vtg##g##_7, a3);

// D[to=lane] = sum_from E[from]*vt[from][lane]; broadcasts pipelined one
// group of 8 ahead of their consumers, all in named scalars.
#define MATVEC(D) \
    { float a0 = 0.f, a1 = 0.f, a2 = 0.f, a3 = 0.f; \
      float tA0,tA1,tA2,tA3,tA4,tA5,tA6,tA7; \
      float tB0,tB1,tB2,tB3,tB4,tB5,tB6,tB7; \
      RL_GROUP(tA, 0) \
      RL_GROUP(tB, 1) FMA_GROUP(tA, 0) \
      RL_GROUP(tA, 2) FMA_GROUP(tB, 1) \
      RL_GROUP(tB, 3) FMA_GROUP(tA, 2) \
      RL_GROUP(tA, 4) FMA_GROUP(tB, 3) \
      RL_GROUP(tB, 5) FMA_GROUP(tA, 4) \
      RL_GROUP(tA, 6) FMA_GROUP(tB, 5) \
      RL_GROUP(tB, 7) FMA_GROUP(tA, 6) \
      FMA_GROUP(tB, 7) \
      (D) = (a0 + a1) + (a2 + a3); }

// one scan step; scale = 2^-kpend from the PREVIOUS step's D exponent
#define STEP(FRJ) \
    { const float fe = __builtin_amdgcn_exp2f((FRJ) * LOG2E) * scale; \
      ksum += kpend; \
      float D; MATVEC(D) \
      const int eb = (__builtin_amdgcn_readfirstlane(__float_as_int(D)) \
                      >> 23) & 0xff; \
      kpend = eb - 127; \
      scale = __int_as_float((254 - eb) << 23); \
      E = fe * D; }

__global__ __launch_bounds__(128, 1) void crf_main(
    const float* __restrict__ feats, const int* __restrict__ mask,
    const int* __restrict__ tags, const float* __restrict__ trans,
    float* __restrict__ out)
{
    const int b    = blockIdx.x;
    const int tid  = threadIdx.x;
    const int lane = tid & 63;

    const float* frow = feats + (size_t)b * SS * TT;
    const int*   mrow = mask + b * SS;

    if (tid < 64) {
        // ---------------- forward (log partition), one wave per batch --------
        int cnt = 0;
        #pragma unroll
        for (int s = lane; s < SS; s += 64) cnt += (mrow[s] != 0);
        #pragma unroll
        for (int off = 32; off; off >>= 1) cnt += __shfl_xor(cnt, off);
        const int len = cnt;                       // in [SS/2, SS]

        // transfer matrix in exp2 space, 64 named scalars
        VT_GROUP(0) VT_GROUP(1) VT_GROUP(2) VT_GROUP(3)
        VT_GROUP(4) VT_GROUP(5) VT_GROUP(6) VT_GROUP(7)

        // init: P0[to] = f[0,to] + trans[START,to];  E = exp2((P0-offs)*log2e)
        const float P0   = frow[lane] + trans[START_TAG * TT + lane];
        const float offs = bcast0(P0);
        float E = __builtin_amdgcn_exp2f((P0 - offs) * LOG2E);
        int   ksum = 0, kpend = 0;
        float scale = 1.0f;

        // 8-deep feats row ring, named scalars; fr_j = row s+j (s=1)
        float fr0 = frow[1 * TT + lane];
        float fr1 = frow[2 * TT + lane];
        float fr2 = frow[3 * TT + lane];
        float fr3 = frow[4 * TT + lane];
        float fr4 = frow[5 * TT + lane];
        float fr5 = frow[6 * TT + lane];
        float fr6 = frow[7 * TT + lane];
        float fr7 = frow[8 * TT + lane];

        int s = 1;
        for (; s + 3 < len; s += 4) {
            // issue next block's loads (rows s+8..s+11); consumed 8 steps later
            int r0 = s + 8, r1 = s + 9, r2 = s + 10, r3 = s + 11;
            if (r0 > SS - 1) r0 = SS - 1;
            if (r1 > SS - 1) r1 = SS - 1;
            if (r2 > SS - 1) r2 = SS - 1;
            if (r3 > SS - 1) r3 = SS - 1;
            const float n0 = frow[(size_t)r0 * TT + lane];
            const float n1 = frow[(size_t)r1 * TT + lane];
            const float n2 = frow[(size_t)r2 * TT + lane];
            const float n3 = frow[(size_t)r3 * TT + lane];

            STEP(fr0) STEP(fr1) STEP(fr2) STEP(fr3)

            fr0 = fr4; fr1 = fr5; fr2 = fr6; fr3 = fr7;
            fr4 = n0;  fr5 = n1;  fr6 = n2;  fr7 = n3;
        }

        // tail: up to 3 steps, constant ring slots
        const int rem = len - s;   // 0..3
        if (rem > 0) STEP(fr0)
        if (rem > 1) STEP(fr1)
        if (rem > 2) STEP(fr2)

        // final transition to STOP: lse_from(P[from] + trans[from,STOP])
        const float ts = __builtin_amdgcn_exp2f(trans[lane * TT + STOP_TAG] * LOG2E);
        float e = E * ts;
        #pragma unroll
        for (int off = 32; off; off >>= 1) e += __shfl_xor(e, off);

        if (lane == 0)
            atomicAdd(out, offs + (float)ksum * LN2
                           + LN2 * __builtin_amdgcn_logf(e));
    } else {
        // ---------------- gold score, wave 1 of the block --------------------
        const int* trow = tags + b * SS;
        int   cnt = 0;
        float acc = 0.f;
        for (int s = lane; s < SS; s += 64) {
            if (mrow[s] != 0) {
                ++cnt;
                const int tag  = trow[s];
                const int prev = (s == 0) ? START_TAG : trow[s - 1];
                acc += frow[(size_t)s * TT + tag] + trans[prev * TT + tag];
            }
        }
        #pragma unroll
        for (int off = 32; off; off >>= 1) {
            acc += __shfl_xor(acc, off);
            cnt += __shfl_xor(cnt, off);
        }
        if (lane == 0) {
            const int end_id = trow[cnt - 1];
            atomicAdd(out, -(acc + trans[end_id * TT + STOP_TAG]));
        }
    }
}

__global__ void zero_out(float* out) { out[0] = 0.f; }

extern "C" void kernel_launch(void* const* d_in, const int* in_sizes, int n_in,
                              void* d_out, int out_size, void* d_ws, size_t ws_size,
                              hipStream_t stream) {
    const float* feats = (const float*)d_in[0];   // (B,S,T) f32
    const int*   mask  = (const int*)d_in[1];     // (B,S)   int (0/1)
    const int*   tags  = (const int*)d_in[2];     // (B,S)   int
    const float* trans = (const float*)d_in[3];   // (T,T)   f32
    float* out = (float*)d_out;

    zero_out<<<1, 1, 0, stream>>>(out);
    crf_main<<<BB, 128, 0, stream>>>(feats, mask, tags, trans, out);
}

// Round 7
// 205.555 us; speedup vs baseline: 1.0662x; 1.0662x over previous
//
#include <hip/hip_runtime.h>

// CRF NLL, round 7: exp-space forward recursion, one wave per batch.
// Change vs r5 (single variable): __attribute__((amdgpu_waves_per_eu(1,1)))
// — LLVM's register allocator budgets VGPRs for its default occupancy target
// unless an explicit MAX waves/EU is given (launch_bounds' min-waves hint
// provably didn't move it: VGPR_Count stayed 52 with vt[64] live). max=1
// opens the budget to the full SIMD register file; our launch is exactly
// 1 wave/EU (512 blocks x 2 waves on 1024 SIMDs), so it costs nothing.
#define BB 512
#define SS 512
#define TT 64
#define START_TAG 62
#define STOP_TAG 63

#define LOG2E 1.4426950408889634f
#define LN2   0.6931471805599453f

__device__ __forceinline__ float bcast0(float x) {
    return __int_as_float(__builtin_amdgcn_readfirstlane(__float_as_int(x)));
}
__device__ __forceinline__ float rlane(float x, int l) {
    return __int_as_float(__builtin_amdgcn_readlane(__float_as_int(x), l));
}

// D[to=lane] = sum_from E[from] * vt[from]; readlane broadcasts pipelined
// one group of 8 ahead of their fmac consumers. All indices constant.
__device__ __forceinline__ float matvec64(const float E, const float (&vt)[64]) {
    float a0 = 0.f, a1 = 0.f, a2 = 0.f, a3 = 0.f;
    float t[2][8];
    #pragma unroll
    for (int j = 0; j < 8; ++j) t[0][j] = rlane(E, j);
    #pragma unroll
    for (int g = 0; g < 8; ++g) {
        const int cur = g & 1, nxt = cur ^ 1;
        if (g < 7) {
            #pragma unroll
            for (int j = 0; j < 8; ++j) t[nxt][j] = rlane(E, 8 * g + 8 + j);
        }
        a0 = fmaf(t[cur][0], vt[8 * g + 0], a0);
        a1 = fmaf(t[cur][1], vt[8 * g + 1], a1);
        a2 = fmaf(t[cur][2], vt[8 * g + 2], a2);
        a3 = fmaf(t[cur][3], vt[8 * g + 3], a3);
        a0 = fmaf(t[cur][4], vt[8 * g + 4], a0);
        a1 = fmaf(t[cur][5], vt[8 * g + 5], a1);
        a2 = fmaf(t[cur][6], vt[8 * g + 6], a2);
        a3 = fmaf(t[cur][7], vt[8 * g + 7], a3);
    }
    return (a0 + a1) + (a2 + a3);
}

__global__ void __launch_bounds__(128)
__attribute__((amdgpu_waves_per_eu(1, 1))) crf_main(
    const float* __restrict__ feats, const int* __restrict__ mask,
    const int* __restrict__ tags, const float* __restrict__ trans,
    float* __restrict__ out)
{
    const int b    = blockIdx.x;
    const int tid  = threadIdx.x;
    const int lane = tid & 63;

    const float* frow = feats + (size_t)b * SS * TT;
    const int*   mrow = mask + b * SS;

    if (tid < 64) {
        // ---------------- forward (log partition), one wave per batch --------
        int cnt = 0;
        #pragma unroll
        for (int s = lane; s < SS; s += 64) cnt += (mrow[s] != 0);
        #pragma unroll
        for (int off = 32; off; off >>= 1) cnt += __shfl_xor(cnt, off);
        const int len = cnt;                       // in [SS/2, SS]

        // M[from=i][to=lane] in exp2 space (constant across the scan)
        float vt[64];
        #pragma unroll
        for (int i = 0; i < 64; ++i)
            vt[i] = __builtin_amdgcn_exp2f(trans[i * TT + lane] * LOG2E);

        // init: P0[to] = f[0,to] + trans[START,to];  E = exp2((P0-offs)*log2e)
        const float P0   = frow[lane] + trans[START_TAG * TT + lane];
        const float offs = bcast0(P0);
        float E = __builtin_amdgcn_exp2f((P0 - offs) * LOG2E);
        int ksum = 0;

        // 8-deep feats row ring (1 VGPR per row), rows s..s+7 for s=1
        float fr[8];
        #pragma unroll
        for (int j = 0; j < 8; ++j) {
            int r = 1 + j; if (r > SS - 1) r = SS - 1;
            fr[j] = frow[(size_t)r * TT + lane];
        }

        int s = 1;
        for (; s + 3 < len; s += 4) {
            // issue next block's loads (rows s+8..s+11); consumed 8 steps later
            float n0, n1, n2, n3;
            {
                int r0 = s + 8, r1 = s + 9, r2 = s + 10, r3 = s + 11;
                if (r0 > SS - 1) r0 = SS - 1;
                if (r1 > SS - 1) r1 = SS - 1;
                if (r2 > SS - 1) r2 = SS - 1;
                if (r3 > SS - 1) r3 = SS - 1;
                n0 = frow[(size_t)r0 * TT + lane];
                n1 = frow[(size_t)r1 * TT + lane];
                n2 = frow[(size_t)r2 * TT + lane];
                n3 = frow[(size_t)r3 * TT + lane];
            }

            // 3 plain steps (no rescale; growth bounded < 2^16/step)
            #pragma unroll
            for (int j = 0; j < 3; ++j) {
                const float fe = __builtin_amdgcn_exp2f(fr[j] * LOG2E);
                const float D  = matvec64(E, vt);
                E = fe * D;
            }
            // 4th step with exact pow2 rescale
            {
                const float fe = __builtin_amdgcn_exp2f(fr[3] * LOG2E);
                const float D  = matvec64(E, vt);
                const int ebits = (__builtin_amdgcn_readfirstlane(
                                       __float_as_int(D)) >> 23) & 0xff;
                ksum += ebits - 127;
                const float scale = __int_as_float((254 - ebits) << 23);
                E = fe * (D * scale);
            }

            // ring shift, constant indices -> pure register renaming
            #pragma unroll
            for (int j = 0; j < 4; ++j) fr[j] = fr[j + 4];
            fr[4] = n0; fr[5] = n1; fr[6] = n2; fr[7] = n3;
        }

        // tail: up to 3 steps, constant-index guarded (no dynamic fr[j])
        const int rem = len - s;   // 0..3
        #pragma unroll
        for (int j = 0; j < 3; ++j) {
            if (j < rem) {
                const float fe = __builtin_amdgcn_exp2f(fr[j] * LOG2E);
                const float D  = matvec64(E, vt);
                const int ebits = (__builtin_amdgcn_readfirstlane(
                                       __float_as_int(D)) >> 23) & 0xff;
                ksum += ebits - 127;
                const float scale = __int_as_float((254 - ebits) << 23);
                E = fe * (D * scale);
            }
        }

        // final transition to STOP: lse_from(P[from] + trans[from,STOP])
        const float ts = __builtin_amdgcn_exp2f(trans[lane * TT + STOP_TAG] * LOG2E);
        float e = E * ts;
        #pragma unroll
        for (int off = 32; off; off >>= 1) e += __shfl_xor(e, off);

        if (lane == 0)
            atomicAdd(out, offs + (float)ksum * LN2
                           + LN2 * __builtin_amdgcn_logf(e));
    } else {
        // ---------------- gold score, wave 1 of the block --------------------
        const int* trow = tags + b * SS;
        int   cnt = 0;
        float acc = 0.f;
        for (int s = lane; s < SS; s += 64) {
            if (mrow[s] != 0) {
                ++cnt;
                const int tag  = trow[s];
                const int prev = (s == 0) ? START_TAG : trow[s - 1];
                acc += frow[(size_t)s * TT + tag] + trans[prev * TT + tag];
            }
        }
        #pragma unroll
        for (int off = 32; off; off >>= 1) {
            acc += __shfl_xor(acc, off);
            cnt += __shfl_xor(cnt, off);
        }
        if (lane == 0) {
            const int end_id = trow[cnt - 1];
            atomicAdd(out, -(acc + trans[end_id * TT + STOP_TAG]));
        }
    }
}

__global__ void zero_out(float* out) { out[0] = 0.f; }

extern "C" void kernel_launch(void* const* d_in, const int* in_sizes, int n_in,
                              void* d_out, int out_size, void* d_ws, size_t ws_size,
                              hipStream_t stream) {
    const float* feats = (const float*)d_in[0];   // (B,S,T) f32
    const int*   mask  = (const int*)d_in[1];     // (B,S)   int (0/1)
    const int*   tags  = (const int*)d_in[2];     // (B,S)   int
    const float* trans = (const float*)d_in[3];   // (T,T)   f32
    float* out = (float*)d_out;

    zero_out<<<1, 1, 0, stream>>>(out);
    crf_main<<<BB, 128, 0, stream>>>(feats, mask, tags, trans, out);
}

// Round 8
// 204.915 us; speedup vs baseline: 1.0695x; 1.0031x over previous
//
#include <hip/hip_runtime.h>

// CRF NLL, round 8: forward recursion stepped on the MFMA pipe.
// The matvec D[to] = sum_from E[from]*M[from,to] is done by 8
// mfma_f32_16x16x32_bf16 (4 'to'-tiles x 2 k-chunks) with E's row
// replicated across all 16 M-rows (read same LDS row for every lane ->
// all D rows identical; reg 0 of each acc holds D[.][lane&15]).
// This deletes the 64x(v_readlane->v_fmac) scalar-broadcast loop whose
// ~9.3 cyc/pair stall was invariant across R2-R7.
#define BB 512
#define SS 512
#define TT 64
#define START_TAG 62
#define STOP_TAG 63

#define LOG2E 1.4426950408889634f
#define LN2   0.6931471805599453f

typedef short bf16x8 __attribute__((ext_vector_type(8)));
typedef float f32x4  __attribute__((ext_vector_type(4)));

__device__ __forceinline__ float bcast0f(float x) {
    return __int_as_float(__builtin_amdgcn_readfirstlane(__float_as_int(x)));
}
// f32 -> bf16 bits, round-to-nearest-even
__device__ __forceinline__ unsigned short f2bf(float x) {
    unsigned u = __float_as_uint(x);
    return (unsigned short)((u + 0x7FFFu + ((u >> 16) & 1u)) >> 16);
}

// One scan step. FT = float[4] feats row (to = (lane&15)+16t).
// Stale pow2 rescale: kprev (exponent of previous step's D at to=0) is
// folded into fe's exp2 argument; ksum tracks applied scales.
#define MSTEP(FT) { \
    const float kf = (float)kprev; ksum += kprev; \
    const float fe0 = __builtin_amdgcn_exp2f((FT)[0] * LOG2E - kf); \
    const float fe1 = __builtin_amdgcn_exp2f((FT)[1] * LOG2E - kf); \
    const float fe2 = __builtin_amdgcn_exp2f((FT)[2] * LOG2E - kf); \
    const float fe3 = __builtin_amdgcn_exp2f((FT)[3] * LOG2E - kf); \
    const bf16x8 a0 = *(const bf16x8*)((const char*)Ebuf + ((lane >> 4) * 16)); \
    const bf16x8 a1 = *(const bf16x8*)((const char*)Ebuf + 64 + ((lane >> 4) * 16)); \
    f32x4 ac0 = __builtin_amdgcn_mfma_f32_16x16x32_bf16(a0, Bf[0][0], Z, 0, 0, 0); \
    f32x4 ac1 = __builtin_amdgcn_mfma_f32_16x16x32_bf16(a0, Bf[0][1], Z, 0, 0, 0); \
    f32x4 ac2 = __builtin_amdgcn_mfma_f32_16x16x32_bf16(a0, Bf[0][2], Z, 0, 0, 0); \
    f32x4 ac3 = __builtin_amdgcn_mfma_f32_16x16x32_bf16(a0, Bf[0][3], Z, 0, 0, 0); \
    ac0 = __builtin_amdgcn_mfma_f32_16x16x32_bf16(a1, Bf[1][0], ac0, 0, 0, 0); \
    ac1 = __builtin_amdgcn_mfma_f32_16x16x32_bf16(a1, Bf[1][1], ac1, 0, 0, 0); \
    ac2 = __builtin_amdgcn_mfma_f32_16x16x32_bf16(a1, Bf[1][2], ac2, 0, 0, 0); \
    ac3 = __builtin_amdgcn_mfma_f32_16x16x32_bf16(a1, Bf[1][3], ac3, 0, 0, 0); \
    const int eb = (__builtin_amdgcn_readfirstlane(__float_as_int(ac0[0])) >> 23) & 0xff; \
    kprev = eb - 127; \
    const float v0 = fe0 * ac0[0]; \
    const float v1 = fe1 * ac1[0]; \
    const float v2 = fe2 * ac2[0]; \
    const float v3 = fe3 * ac3[0]; \
    if (lane < 16) { \
        Ebuf[lane     ] = f2bf(v0); \
        Ebuf[lane + 16] = f2bf(v1); \
        Ebuf[lane + 32] = f2bf(v2); \
        Ebuf[lane + 48] = f2bf(v3); \
    } }

__global__ void __launch_bounds__(128)
__attribute__((amdgpu_waves_per_eu(1, 1))) crf_main(
    const float* __restrict__ feats, const int* __restrict__ mask,
    const int* __restrict__ tags, const float* __restrict__ trans,
    float* __restrict__ out)
{
    const int b    = blockIdx.x;
    const int tid  = threadIdx.x;
    const int lane = tid & 63;

    const float* frow = feats + (size_t)b * SS * TT;
    const int*   mrow = mask + b * SS;

    // E_s as 64 bf16, A-layout row (to = index); used by wave 0 only
    __shared__ __align__(16) unsigned short Ebuf[TT];

    if (tid < 64) {
        // ---- sequence length ----
        int cnt = 0;
        #pragma unroll
        for (int s = lane; s < SS; s += 64) cnt += (mrow[s] != 0);
        #pragma unroll
        for (int off = 32; off; off >>= 1) cnt += __shfl_xor(cnt, off);
        const int len = cnt;                       // in [SS/2, SS]

        // ---- B fragments: M = exp2(trans*log2e) in bf16 ----
        // B[k=from][n=to_tile]: lane element j = M[c*32+(lane>>4)*8+j][(lane&15)+16t]
        bf16x8 Bf[2][4];
        #pragma unroll
        for (int c = 0; c < 2; ++c)
            #pragma unroll
            for (int t = 0; t < 4; ++t)
                #pragma unroll
                for (int j = 0; j < 8; ++j) {
                    const int from = c * 32 + (lane >> 4) * 8 + j;
                    const int to   = (lane & 15) + 16 * t;
                    Bf[c][t][j] = (short)f2bf(
                        __builtin_amdgcn_exp2f(trans[from * TT + to] * LOG2E));
                }

        const f32x4 Z = {0.f, 0.f, 0.f, 0.f};

        // ---- init: P0[to] = f[0,to] + trans[START,to] ----
        float P0t[4];
        #pragma unroll
        for (int t = 0; t < 4; ++t)
            P0t[t] = frow[(lane & 15) + 16 * t]
                   + trans[START_TAG * TT + (lane & 15) + 16 * t];
        const float offs2 = bcast0f(P0t[0] * LOG2E);   // lane0 -> to=0
        if (lane < 16) {
            #pragma unroll
            for (int t = 0; t < 4; ++t)
                Ebuf[lane + 16 * t] =
                    f2bf(__builtin_amdgcn_exp2f(P0t[t] * LOG2E - offs2));
        }

        // ---- feats ring: rows 1..8, 4 values per row ----
        float ring[8][4];
        #pragma unroll
        for (int r = 0; r < 8; ++r)
            #pragma unroll
            for (int t = 0; t < 4; ++t)
                ring[r][t] = frow[(size_t)(1 + r) * TT + (lane & 15) + 16 * t];

        int ksum = 0, kprev = 0;

        int s = 1;
        for (; s + 3 < len; s += 4) {
            // issue rows s+8..s+11 (consumed 1-2 iterations later)
            float nr[4][4];
            #pragma unroll
            for (int q = 0; q < 4; ++q) {
                int rr = s + 8 + q; if (rr > SS - 1) rr = SS - 1;
                #pragma unroll
                for (int t = 0; t < 4; ++t)
                    nr[q][t] = frow[(size_t)rr * TT + (lane & 15) + 16 * t];
            }

            MSTEP(ring[0]) MSTEP(ring[1]) MSTEP(ring[2]) MSTEP(ring[3])

            #pragma unroll
            for (int u = 0; u < 4; ++u)
                #pragma unroll
                for (int t = 0; t < 4; ++t) ring[u][t] = ring[u + 4][t];
            #pragma unroll
            for (int q = 0; q < 4; ++q)
                #pragma unroll
                for (int t = 0; t < 4; ++t) ring[4 + q][t] = nr[q][t];
        }
        const int rem = len - s;   // 0..3 steps left (steps s..len-1)
        if (rem > 0) { MSTEP(ring[0]) }
        if (rem > 1) { MSTEP(ring[1]) }
        if (rem > 2) { MSTEP(ring[2]) }

        // ---- final transition to STOP ----
        const unsigned short ev = Ebuf[lane];
        const float Ev = __int_as_float(((int)ev) << 16);
        const float Ms = __builtin_amdgcn_exp2f(trans[lane * TT + STOP_TAG] * LOG2E);
        float e = Ev * Ms;
        #pragma unroll
        for (int off = 32; off; off >>= 1) e += __shfl_xor(e, off);

        if (lane == 0)
            atomicAdd(out, LN2 * (offs2 + (float)ksum
                                  + __builtin_amdgcn_logf(e)));
    } else {
        // ---------------- gold score, wave 1 of the block --------------------
        const int* trow = tags + b * SS;
        int   cnt = 0;
        float acc = 0.f;
        for (int s = lane; s < SS; s += 64) {
            if (mrow[s] != 0) {
                ++cnt;
                const int tag  = trow[s];
                const int prev = (s == 0) ? START_TAG : trow[s - 1];
                acc += frow[(size_t)s * TT + tag] + trans[prev * TT + tag];
            }
        }
        #pragma unroll
        for (int off = 32; off; off >>= 1) {
            acc += __shfl_xor(acc, off);
            cnt += __shfl_xor(cnt, off);
        }
        if (lane == 0) {
            const int end_id = trow[cnt - 1];
            atomicAdd(out, -(acc + trans[end_id * TT + STOP_TAG]));
        }
    }
}

__global__ void zero_out(float* out) { out[0] = 0.f; }

extern "C" void kernel_launch(void* const* d_in, const int* in_sizes, int n_in,
                              void* d_out, int out_size, void* d_ws, size_t ws_size,
                              hipStream_t stream) {
    const float* feats = (const float*)d_in[0];   // (B,S,T) f32
    const int*   mask  = (const int*)d_in[1];     // (B,S)   int (0/1)
    const int*   tags  = (const int*)d_in[2];     // (B,S)   int
    const float* trans = (const float*)d_in[3];   // (T,T)   f32
    float* out = (float*)d_out;

    zero_out<<<1, 1, 0, stream>>>(out);
    crf_main<<<BB, 128, 0, stream>>>(feats, mask, tags, trans, out);
}